// Round 7
// baseline (325.894 us; speedup 1.0000x reference)
//
#include <hip/hip_runtime.h>

#define N_NODES 100000
#define N_EDGES 6400000
#define D 12

#define SLOG 7
#define SSZ  128                           // nodes per bucket
#define NB   ((N_NODES + SSZ - 1) / SSZ)   // 782 buckets
#define SBLK 256                           // partition blocks
#define STHR 512
#define SEPB (N_EDGES / SBLK)              // 25000 edges per block (exact)

#define CAP  1280                          // edges per chunk in agg pass
#define SLOT 7                             // vals slot stride (coprime 32 banks)

// ---- bf16 helpers ----------------------------------------------------------
__device__ __forceinline__ unsigned int f2bf(float f) {
    unsigned int u = __float_as_uint(f);
    return (u + 0x7fffu + ((u >> 16) & 1u)) >> 16;   // RTNE
}
__device__ __forceinline__ unsigned int pk2(float lo, float hi) {
    return (f2bf(hi) << 16) | f2bf(lo);
}
__device__ __forceinline__ float bflo(unsigned int u) { return __uint_as_float(u << 16); }
__device__ __forceinline__ float bfhi(unsigned int u) { return __uint_as_float(u & 0xffff0000u); }

// Prep: fp32 x [N,12] -> bf16 xb padded rows of 16 elems (32 B, 3.2 MB total).
__global__ __launch_bounds__(256) void prep_kernel(
    const float* __restrict__ x, unsigned int* __restrict__ xb)
{
    int i = blockIdx.x * 256 + threadIdx.x;
    if (i >= N_NODES) return;
    const float4* xr = (const float4*)(x) + (size_t)i * 3;
    float4 a = xr[0], b = xr[1], c = xr[2];
    unsigned int* o = xb + (size_t)i * 8;
    ((uint4*)o)[0] = make_uint4(pk2(a.x, a.y), pk2(a.z, a.w), pk2(b.x, b.y), pk2(b.z, b.w));
    ((uint2*)(o + 4))[0] = make_uint2(pk2(c.x, c.y), pk2(c.z, c.w));
}

// Partition: block-major output (unchanged from round 6).
__global__ __launch_bounds__(512) void part_kernel(
    const int* __restrict__ ei, int* __restrict__ cnt, int* __restrict__ rowpre,
    unsigned int* __restrict__ sorted)
{
    __shared__ int h[NB];
    __shared__ int cur[NB];
    __shared__ int sb2[512];
    int t = threadIdx.x;
    int b = blockIdx.x;
    for (int i = t; i < NB; i += STHR) h[i] = 0;
    __syncthreads();

    const int* dei = ei + N_EDGES;
    int start = b * SEPB;
    int end = start + SEPB;

    // Phase A: histogram of dst buckets.
    int e = start + t;
    while (e + 3 * STHR < end) {
        int d0 = dei[e], d1 = dei[e + STHR], d2 = dei[e + 2 * STHR], d3 = dei[e + 3 * STHR];
        atomicAdd(&h[d0 >> SLOG], 1);
        atomicAdd(&h[d1 >> SLOG], 1);
        atomicAdd(&h[d2 >> SLOG], 1);
        atomicAdd(&h[d3 >> SLOG], 1);
        e += 4 * STHR;
    }
    while (e < end) { atomicAdd(&h[dei[e] >> SLOG], 1); e += STHR; }
    __syncthreads();

    // Save counts row.
    int* crow = cnt + (size_t)b * NB;
    for (int i = t; i < NB; i += STHR) crow[i] = h[i];

    // In-block exclusive scan of h -> cur (pairs + 512-wide Hillis-Steele).
    int pairv = 0;
    if (t < (NB + 1) / 2) {
        pairv = h[2 * t] + ((2 * t + 1 < NB) ? h[2 * t + 1] : 0);
    }
    sb2[t] = pairv;
    __syncthreads();
    for (int o = 1; o < 512; o <<= 1) {
        int v = (t >= o) ? sb2[t - o] : 0;
        __syncthreads();
        sb2[t] += v;
        __syncthreads();
    }
    if (t < (NB + 1) / 2) {
        int excl = sb2[t] - pairv;
        cur[2 * t] = excl;
        if (2 * t + 1 < NB) cur[2 * t + 1] = excl + h[2 * t];
    }
    __syncthreads();

    // Save in-block bucket starts.
    int* rrow = rowpre + (size_t)b * NB;
    for (int i = t; i < NB; i += STHR) rrow[i] = cur[i];
    __syncthreads();

    // Phase B: place into own region (re-read ei; dei L3-hot).
    unsigned int* dst = sorted + (size_t)b * SEPB;
    e = start + t;
    while (e + 3 * STHR < end) {
        int s0 = ei[e], s1 = ei[e + STHR], s2 = ei[e + 2 * STHR], s3 = ei[e + 3 * STHR];
        int d0 = dei[e], d1 = dei[e + STHR], d2 = dei[e + 2 * STHR], d3 = dei[e + 3 * STHR];
        int p0 = atomicAdd(&cur[d0 >> SLOG], 1);
        int p1 = atomicAdd(&cur[d1 >> SLOG], 1);
        int p2 = atomicAdd(&cur[d2 >> SLOG], 1);
        int p3 = atomicAdd(&cur[d3 >> SLOG], 1);
        dst[p0] = ((unsigned)s0 << SLOG) | (unsigned)(d0 & (SSZ - 1));
        dst[p1] = ((unsigned)s1 << SLOG) | (unsigned)(d1 & (SSZ - 1));
        dst[p2] = ((unsigned)s2 << SLOG) | (unsigned)(d2 & (SSZ - 1));
        dst[p3] = ((unsigned)s3 << SLOG) | (unsigned)(d3 & (SSZ - 1));
        e += 4 * STHR;
    }
    while (e < end) {
        int s = ei[e], d = dei[e];
        int pos = atomicAdd(&cur[d >> SLOG], 1);
        dst[pos] = ((unsigned)s << SLOG) | (unsigned)(d & (SSZ - 1));
        e += STHR;
    }
}

// Agg: one block per bucket. Bucket = 256 per-block segments. Per chunk:
// cooperative segmented COPY (coalesced, no search) into LDS epack, then the
// proven count/scan/place/register-accumulate machinery. vals slots stride 7.
__global__ __launch_bounds__(256) void agg_reg_kernel(
    const unsigned int* __restrict__ sorted, const int* __restrict__ cntm,
    const int* __restrict__ rowpre, const unsigned int* __restrict__ xb,
    const float* __restrict__ x, const float* __restrict__ Wl,
    const float* __restrict__ Wr, const float* __restrict__ bias,
    float* __restrict__ out)
{
    __shared__ float sWl[D * D], sWr[D * D], sb[D];
    __shared__ int cnt[SSZ];
    __shared__ int sbuf[SSZ];
    __shared__ int segbase[SSZ + 1];
    __shared__ int cursor[SSZ];
    __shared__ int cnt_tot[SSZ];
    __shared__ int seglen[SBLK];
    __shared__ int segoff[SBLK];         // global start of segment in sorted[]
    __shared__ int segpre[SBLK + 1];     // prefix of seglen (virtual stream)
    __shared__ int swin;                 // first segment of current window
    __shared__ unsigned epack[CAP];      // staged packed edges (5 KB)
    __shared__ unsigned vals[CAP * SLOT]; // 35.8 KB; reused as red[] at the end

    int t = threadIdx.x;
    int k = blockIdx.x;                  // bucket id

    if (t < D * D) { sWl[t] = Wl[t]; sWr[t] = Wr[t]; }
    if (t < D) sb[t] = bias[t];
    if (t < SSZ) cnt_tot[t] = 0;
    if (t == 0) swin = 0;

    // Load this bucket's segment table (column k of cnt/rowpre matrices).
    if (t < SBLK) {
        seglen[t] = cntm[(size_t)t * NB + k];
        segoff[t] = t * SEPB + rowpre[(size_t)t * NB + k];
    }
    __syncthreads();
    // Prefix over 256 segments (Hillis-Steele on segpre).
    if (t < SBLK) segpre[t + 1] = seglen[t];
    if (t == 0) segpre[0] = 0;
    __syncthreads();
    for (int o = 1; o < SBLK; o <<= 1) {
        int v = 0;
        if (t < SBLK && t + 1 > o) v = segpre[t + 1 - o];
        __syncthreads();
        if (t < SBLK) segpre[t + 1] += v;
        __syncthreads();
    }
    int T = segpre[SBLK];

    float acc[D];
#pragma unroll
    for (int d = 0; d < D; ++d) acc[d] = 0.f;

    int loc = t >> 1;       // node owned in accumulate phase (2 thr/node)
    int sub = t & 1;
    int wave = t >> 6;
    int lane = t & 63;

    for (int c0 = 0; c0 < T; c0 += CAP) {
        int n = min(CAP, T - c0);
        int c1 = c0 + n;
        // Advance window: first segment with segpre[s+1] > c0.
        if (t == 0) {
            int s = swin;
            while (segpre[s + 1] <= c0) ++s;
            swin = s;
        }
        if (t < SSZ) cnt[t] = 0;
        __syncthreads();

        // Segmented copy: wave w takes segments s0w+w, s0w+w+4, ...
        // Each segment is a contiguous run in sorted[] -> coalesced loads.
        int s0w = swin;
        for (int s = s0w + wave; s < SBLK && segpre[s] < c1; s += 4) {
            int vs = segpre[s], ve = segpre[s + 1];
            int a0 = vs > c0 ? vs : c0;
            int a1 = ve < c1 ? ve : c1;
            int len = a1 - a0;
            if (len > 0) {
                int goff = segoff[s] + (a0 - vs);
                int doff = a0 - c0;
                for (int j = lane; j < len; j += 64)
                    epack[doff + j] = sorted[goff + j];
            }
        }
        __syncthreads();

        // Count nodes.
        for (int j = t; j < n; j += 256)
            atomicAdd(&cnt[epack[j] & (SSZ - 1)], 1);
        __syncthreads();

        // Block-wide Hillis-Steele scan of 128 counters.
        if (t < SSZ) sbuf[t] = cnt[t];
        __syncthreads();
        for (int o = 1; o < SSZ; o <<= 1) {
            int v = (t < SSZ && t >= o) ? sbuf[t - o] : 0;
            __syncthreads();
            if (t < SSZ) sbuf[t] += v;
            __syncthreads();
        }
        if (t < SSZ) {
            segbase[t + 1] = sbuf[t];
            if (t == 0) segbase[0] = 0;
        }
        __syncthreads();
        if (t < SSZ) { cursor[t] = segbase[t]; cnt_tot[t] += cnt[t]; }
        __syncthreads();

        // Place: gather bf16 row from xb (L2/L3-hot), write to node's segment.
        for (int j = t; j < n; j += 256) {
            unsigned p = epack[j];
            int slot = atomicAdd(&cursor[p & (SSZ - 1)], 1);
            const unsigned* r = xb + (size_t)(p >> SLOG) * 8;
            uint4 q01 = ((const uint4*)r)[0];
            uint2 w2  = ((const uint2*)(r + 4))[0];
            unsigned* vv = &vals[slot * SLOT];
            vv[0] = q01.x; vv[1] = q01.y; vv[2] = q01.z;
            vv[3] = q01.w; vv[4] = w2.x;  vv[5] = w2.y;
        }
        __syncthreads();

        // Accumulate: thread (loc, sub) scans its node's segment, registers only.
        int s0 = segbase[loc], s1 = segbase[loc + 1];
        for (int j = s0 + sub; j < s1; j += 2) {
            const unsigned* vv = &vals[j * SLOT];
            unsigned a0 = vv[0], a1 = vv[1], a2 = vv[2];
            unsigned a3 = vv[3], a4 = vv[4], a5 = vv[5];
            acc[0]  += bflo(a0); acc[1]  += bfhi(a0);
            acc[2]  += bflo(a1); acc[3]  += bfhi(a1);
            acc[4]  += bflo(a2); acc[5]  += bfhi(a2);
            acc[6]  += bflo(a3); acc[7]  += bfhi(a3);
            acc[8]  += bflo(a4); acc[9]  += bfhi(a4);
            acc[10] += bflo(a5); acc[11] += bfhi(a5);
        }
        __syncthreads();   // before next chunk reuses cnt/vals/epack
    }

    // Reduce the 2 partials per node via LDS overlay (stride 13 vs 32 banks).
    float* red = (float*)vals;   // needs 2*1664 = 3328 floats <= CAP*SLOT = 8960
#pragma unroll
    for (int d = 0; d < D; ++d) red[sub * 1664 + loc * 13 + d] = acc[d];
    __syncthreads();

    if (t < SSZ) {
        int node = k * SSZ + t;
        if (node < N_NODES) {
            float m[D];
#pragma unroll
            for (int d = 0; d < D; ++d)
                m[d] = red[t * 13 + d] + red[1664 + t * 13 + d];
            float inv = 1.f / fmaxf((float)cnt_tot[t], 1.f);
#pragma unroll
            for (int d = 0; d < D; ++d) m[d] *= inv;

            float xi[D];
            const float4* xr = (const float4*)(x) + (size_t)node * 3;
            float4 x0 = xr[0], x1 = xr[1], x2 = xr[2];
            xi[0] = x0.x; xi[1] = x0.y; xi[2]  = x0.z; xi[3]  = x0.w;
            xi[4] = x1.x; xi[5] = x1.y; xi[6]  = x1.z; xi[7]  = x1.w;
            xi[8] = x2.x; xi[9] = x2.y; xi[10] = x2.z; xi[11] = x2.w;

            float o[D];
#pragma unroll
            for (int oo = 0; oo < D; ++oo) {
                float a = sb[oo];
#pragma unroll
                for (int d = 0; d < D; ++d) {
                    a += m[d] * sWl[oo * D + d];
                    a += xi[d] * sWr[oo * D + d];
                }
                o[oo] = a;
            }
            float4* orow = (float4*)(out) + (size_t)node * 3;
            orow[0] = make_float4(o[0], o[1], o[2], o[3]);
            orow[1] = make_float4(o[4], o[5], o[6], o[7]);
            orow[2] = make_float4(o[8], o[9], o[10], o[11]);
        }
    }
}

// ---------------- Last-resort fallback: global atomics ----------------------

__global__ __launch_bounds__(256) void scatter_kernel(
    const int* __restrict__ ei, const float* __restrict__ x,
    float* __restrict__ agg, float* __restrict__ cnt)
{
    int e = blockIdx.x * blockDim.x + threadIdx.x;
    if (e >= N_EDGES) return;
    int src = ei[e];
    int dst = ei[N_EDGES + e];
    const float4* xr = (const float4*)(x + (size_t)src * D);
    float4 a = xr[0], b4 = xr[1], c = xr[2];
    float* dr = agg + (size_t)dst * D;
    atomicAdd(dr + 0,  a.x);  atomicAdd(dr + 1,  a.y);
    atomicAdd(dr + 2,  a.z);  atomicAdd(dr + 3,  a.w);
    atomicAdd(dr + 4,  b4.x); atomicAdd(dr + 5,  b4.y);
    atomicAdd(dr + 6,  b4.z); atomicAdd(dr + 7,  b4.w);
    atomicAdd(dr + 8,  c.x);  atomicAdd(dr + 9,  c.y);
    atomicAdd(dr + 10, c.z);  atomicAdd(dr + 11, c.w);
    atomicAdd(cnt + dst, 1.0f);
}

__global__ __launch_bounds__(256) void finalize_kernel(
    const float* __restrict__ x, const float* __restrict__ Wl,
    const float* __restrict__ Wr, const float* __restrict__ bias,
    const float* __restrict__ agg, const float* __restrict__ cnt,
    float* __restrict__ out)
{
    __shared__ float sWl[D * D], sWr[D * D], sb[D];
    int t = threadIdx.x;
    if (t < D * D) { sWl[t] = Wl[t]; sWr[t] = Wr[t]; }
    if (t < D) sb[t] = bias[t];
    __syncthreads();
    int i = blockIdx.x * blockDim.x + t;
    if (i >= N_NODES) return;
    float inv = 1.0f / fmaxf(cnt[i], 1.0f);
    float m[D], xi[D];
    const float4* ar = (const float4*)(agg + (size_t)i * D);
    const float4* xr = (const float4*)(x + (size_t)i * D);
    float4 a0 = ar[0], a1 = ar[1], a2 = ar[2];
    float4 x0 = xr[0], x1 = xr[1], x2 = xr[2];
    m[0] = a0.x * inv; m[1] = a0.y * inv; m[2]  = a0.z * inv; m[3]  = a0.w * inv;
    m[4] = a1.x * inv; m[5] = a1.y * inv; m[6]  = a1.z * inv; m[7]  = a1.w * inv;
    m[8] = a2.x * inv; m[9] = a2.y * inv; m[10] = a2.z * inv; m[11] = a2.w * inv;
    xi[0] = x0.x; xi[1] = x0.y; xi[2]  = x0.z; xi[3]  = x0.w;
    xi[4] = x1.x; xi[5] = x1.y; xi[6]  = x1.z; xi[7]  = x1.w;
    xi[8] = x2.x; xi[9] = x2.y; xi[10] = x2.z; xi[11] = x2.w;
    float o[D];
#pragma unroll
    for (int oo = 0; oo < D; ++oo) {
        float acc = sb[oo];
#pragma unroll
        for (int d = 0; d < D; ++d) {
            acc += m[d] * sWl[oo * D + d];
            acc += xi[d] * sWr[oo * D + d];
        }
        o[oo] = acc;
    }
    float4* orow = (float4*)(out + (size_t)i * D);
    orow[0] = make_float4(o[0], o[1], o[2], o[3]);
    orow[1] = make_float4(o[4], o[5], o[6], o[7]);
    orow[2] = make_float4(o[8], o[9], o[10], o[11]);
}

extern "C" void kernel_launch(void* const* d_in, const int* in_sizes, int n_in,
                              void* d_out, int out_size, void* d_ws, size_t ws_size,
                              hipStream_t stream) {
    const float* x    = (const float*)d_in[0];
    const float* Wl   = (const float*)d_in[1];
    const float* Wr   = (const float*)d_in[2];
    const float* bias = (const float*)d_in[3];
    const int*   ei   = (const int*)d_in[4];
    float* out = (float*)d_out;

    size_t sortedBytes = (size_t)N_EDGES * sizeof(unsigned int);     // 25.6 MB
    size_t xbBytes     = (size_t)N_NODES * 8 * sizeof(unsigned int); // 3.2 MB
    size_t cntBytes    = (size_t)SBLK * NB * sizeof(int);            // 0.8 MB
    size_t rowpreBytes = cntBytes;                                   // 0.8 MB
    size_t neededFull = sortedBytes + xbBytes + cntBytes + rowpreBytes;
    size_t neededLast = ((size_t)N_NODES * D + N_NODES) * sizeof(float);

    if (ws_size >= neededFull) {
        char* p = (char*)d_ws;
        unsigned int* sorted = (unsigned int*)p;        p += sortedBytes;
        unsigned int* xb     = (unsigned int*)p;        p += xbBytes;
        int* cnt    = (int*)p;                          p += cntBytes;
        int* rowpre = (int*)p;

        prep_kernel<<<(N_NODES + 255) / 256, 256, 0, stream>>>(x, xb);
        part_kernel<<<SBLK, STHR, 0, stream>>>(ei, cnt, rowpre, sorted);
        agg_reg_kernel<<<NB, 256, 0, stream>>>(sorted, cnt, rowpre, xb, x, Wl, Wr, bias, out);
    } else {
        float* agg = (float*)d_ws;
        float* cnt = agg + (size_t)N_NODES * D;
        hipMemsetAsync(d_ws, 0, neededLast, stream);
        scatter_kernel<<<(N_EDGES + 255) / 256, 256, 0, stream>>>(ei, x, agg, cnt);
        finalize_kernel<<<(N_NODES + 255) / 256, 256, 0, stream>>>(x, Wl, Wr, bias, agg, cnt, out);
    }
}